// Round 13
// baseline (895.938 us; speedup 1.0000x reference)
//
#include <hip/hip_runtime.h>
#include <hip/hip_bf16.h>

#define FDIM 256

typedef float f32x4 __attribute__((ext_vector_type(4)));
typedef _Float16 f16x4 __attribute__((ext_vector_type(4)));
typedef _Float16 f16x8 __attribute__((ext_vector_type(8)));

// ---------------- CSR build ----------------

__global__ void zero_counts_k(int* counts, int Nn) {
    int i = blockIdx.x * 256 + threadIdx.x;
    if (i < Nn) counts[i] = 0;
}

__global__ void count_edges_k(const int* __restrict__ esrc, int* counts, int Ee) {
    int e = blockIdx.x * 256 + threadIdx.x;
    if (e < Ee) atomicAdd(&counts[esrc[e]], 1);
}

__global__ void dinv_k(const int* __restrict__ counts, float* __restrict__ dinv, int Nn) {
    int i = blockIdx.x * 256 + threadIdx.x;
    if (i < Nn) dinv[i] = rsqrtf((float)(counts[i] + 1));   // +1 self-loop, always > 0
}

// exclusive scan, 1024 elems / block
__global__ __launch_bounds__(256) void scanA_k(const int* __restrict__ counts,
                                               int* __restrict__ rowptr,
                                               int* __restrict__ bsum, int Nn) {
    __shared__ int sh[256];
    int tid = threadIdx.x;
    int base = blockIdx.x * 1024 + tid * 4;
    int v[4];
#pragma unroll
    for (int j = 0; j < 4; ++j) v[j] = (base + j < Nn) ? counts[base + j] : 0;
    int ts = v[0] + v[1] + v[2] + v[3];
    sh[tid] = ts;
    __syncthreads();
    for (int off = 1; off < 256; off <<= 1) {
        int x = (tid >= off) ? sh[tid - off] : 0;
        __syncthreads();
        sh[tid] += x;
        __syncthreads();
    }
    int excl = sh[tid] - ts;
    if (tid == 255) bsum[blockIdx.x] = sh[255];
    int run = excl;
#pragma unroll
    for (int j = 0; j < 4; ++j) {
        if (base + j < Nn) rowptr[base + j] = run;
        run += v[j];
    }
}

__global__ __launch_bounds__(256) void scanB_k(int* bsum, int nb) {
    __shared__ int sh[256];
    int tid = threadIdx.x;
    int v = (tid < nb) ? bsum[tid] : 0;
    sh[tid] = v;
    __syncthreads();
    for (int off = 1; off < 256; off <<= 1) {
        int x = (tid >= off) ? sh[tid - off] : 0;
        __syncthreads();
        sh[tid] += x;
        __syncthreads();
    }
    if (tid < nb) bsum[tid] = sh[tid] - v;   // exclusive
}

__global__ void scanC_k(int* rowptr, const int* __restrict__ bsum, int* counts, int Nn, int Ee) {
    int i = blockIdx.x * 256 + threadIdx.x;
    if (i < Nn) {
        rowptr[i] += bsum[i >> 10];
        counts[i] = 0;   // reuse as fill cursors
    }
    if (i == 0) rowptr[Nn] = Ee;
}

__global__ void fill_csr_k(const int* __restrict__ esrc, const int* __restrict__ edst,
                           const int* __restrict__ rowptr, int* counts, int* col, int Ee) {
    int e = blockIdx.x * 256 + threadIdx.x;
    if (e < Ee) {
        int d = esrc[e];
        int pos = rowptr[d] + atomicAdd(&counts[d], 1);
        col[pos] = edst[e];
    }
}

// ---------------- casts ----------------

__global__ void cast_x_k(const float* __restrict__ x, _Float16* __restrict__ o, int n) {
    int i = (blockIdx.x * 256 + threadIdx.x) * 4;
    if (i < n) {
        float4 v = *reinterpret_cast<const float4*>(&x[i]);
        f16x4 h = {(_Float16)v.x, (_Float16)v.y, (_Float16)v.z, (_Float16)v.w};
        *reinterpret_cast<f16x4*>(&o[i]) = h;
    }
}

// Wt[z][n][k] = W_z[k][n], fp16
__global__ void castW_k(const float* __restrict__ W0, const float* __restrict__ W1,
                        const float* __restrict__ W2, const float* __restrict__ W3,
                        _Float16* __restrict__ Wt) {
    const float* Ws[4] = {W0, W1, W2, W3};
    const float* W = Ws[blockIdx.y];
    int n = blockIdx.x;
    int k = threadIdx.x;
    Wt[((size_t)blockIdx.y << 16) + n * 256 + k] = (_Float16)W[k * 256 + n];
}

// ---------------- MFMA GEMM: T[i,:] = dinv[i] * (H[i,:] @ W)  (fp16 in, fp16 out) ----------------
// 128x128 tile, BK=64, 4 waves (2x2), each wave 64x64 via 4x4 frags of 16x16x32.

#define GBM 128
#define GBK 64

__global__ __launch_bounds__(256) void gemm_mfma_k(const _Float16* __restrict__ A,
                                                   const _Float16* __restrict__ Wt,
                                                   const float* __restrict__ dinv,
                                                   _Float16* __restrict__ T, int M) {
    __shared__ __align__(16) char smem[32768];
    _Float16* As = (_Float16*)smem;            // [128][64] swizzled
    _Float16* Bs = As + GBM * GBK;             // [128][64] swizzled (Bs[n][k])

    int tid = threadIdx.x;
    int lane = tid & 63;
    int wave = tid >> 6;
    int wm = (wave >> 1) * 64;
    int wn = (wave & 1) * 64;
    int rowBase = blockIdx.x * GBM;
    int colBase = blockIdx.y * 128;

    f32x4 acc[4][4] = {};

    for (int k0 = 0; k0 < FDIM; k0 += GBK) {
        // stage: 1024 16B-chunks each for A and B; 4 per thread
#pragma unroll
        for (int it = 0; it < 4; ++it) {
            int chunk = tid + it * 256;
            int r = chunk >> 3;              // 0..127
            int kc = (chunk & 7) * 8;        // 0..56
            int byte = (r * 128 + kc * 2) ^ ((r & 7) << 4);
            int grow = rowBase + r;
            uint4 av = make_uint4(0, 0, 0, 0);
            if (grow < M) av = *reinterpret_cast<const uint4*>(&A[(size_t)grow * FDIM + k0 + kc]);
            *reinterpret_cast<uint4*>((char*)As + byte) = av;
            uint4 bv = *reinterpret_cast<const uint4*>(&Wt[(size_t)(colBase + r) * FDIM + k0 + kc]);
            *reinterpret_cast<uint4*>((char*)Bs + byte) = bv;
        }
        __syncthreads();
#pragma unroll
        for (int ks = 0; ks < 2; ++ks) {
            int kk = ks * 32 + (lane >> 4) * 8;
            f16x8 af[4], bf[4];
#pragma unroll
            for (int mi = 0; mi < 4; ++mi) {
                int r = wm + mi * 16 + (lane & 15);
                int byte = (r * 128 + kk * 2) ^ ((r & 7) << 4);
                af[mi] = *reinterpret_cast<const f16x8*>((const char*)As + byte);
            }
#pragma unroll
            for (int ni = 0; ni < 4; ++ni) {
                int r = wn + ni * 16 + (lane & 15);
                int byte = (r * 128 + kk * 2) ^ ((r & 7) << 4);
                bf[ni] = *reinterpret_cast<const f16x8*>((const char*)Bs + byte);
            }
#pragma unroll
            for (int mi = 0; mi < 4; ++mi)
#pragma unroll
                for (int ni = 0; ni < 4; ++ni)
                    acc[mi][ni] = __builtin_amdgcn_mfma_f32_16x16x32_f16(af[mi], bf[ni], acc[mi][ni], 0, 0, 0);
        }
        __syncthreads();
    }

    // epilogue: dinv-scale, repack via LDS (swizzled), coalesced fp16 writes
    int cl = lane & 15, rq = lane >> 4;
#pragma unroll
    for (int mi = 0; mi < 4; ++mi) {
#pragma unroll
        for (int r = 0; r < 4; ++r) {
            int lrow = wm + mi * 16 + rq * 4 + r;
            int grow = rowBase + lrow;
            float d = dinv[min(grow, M - 1)];
#pragma unroll
            for (int ni = 0; ni < 4; ++ni) {
                int lcol = wn + ni * 16 + cl;
                int byte = (lrow * 256 + lcol * 2) ^ (((lrow >> 2) & 7) << 5);
                *reinterpret_cast<_Float16*>((char*)smem + byte) = (_Float16)(acc[mi][ni][r] * d);
            }
        }
    }
    __syncthreads();
#pragma unroll
    for (int it = 0; it < 8; ++it) {
        int chunk = tid + it * 256;          // 2048 chunks
        int r = chunk >> 4;                  // 0..127
        int c = (chunk & 15) * 8;            // 0..120
        int byte = (r * 256 + c * 2) ^ (((r >> 2) & 7) << 5);
        uint4 v = *reinterpret_cast<const uint4*>((const char*)smem + byte);
        int grow = rowBase + r;
        if (grow < M) *reinterpret_cast<uint4*>(&T[(size_t)grow * FDIM + colBase + c]) = v;
    }
}

// ---------------- Aggregation (XCD-slice): O[i,fs] = dinv[i]*(T[i,fs] + sum_in T[col,fs]) + b[fs]
// Feature dim split into 8 slices of 32; slice = blockIdx.x & 7 == XCD id under
// round-robin dispatch -> each XCD's L2 holds one 3.2 MB slice of T persistently.
// Wave = one node-slice: lane = (row-group g = lane>>3) x (feature-chunk c = lane&7);
// 8 rows in flight per instruction, 3-stage shfl_xor butterfly folds row groups.

template <int RELU>
__global__ __launch_bounds__(256) void aggs_k(const _Float16* __restrict__ T,
                                              const float* __restrict__ dinv,
                                              const int* __restrict__ rowptr,
                                              const int* __restrict__ col,
                                              const float* __restrict__ bias,
                                              _Float16* __restrict__ O, int Nn) {
    int slice = blockIdx.x & 7;
    int chunk = blockIdx.x >> 3;
    int wave = threadIdx.x >> 6;
    int lane = threadIdx.x & 63;
    int i = chunk * 4 + wave;
    if (i >= Nn) return;
    int g = lane >> 3;                    // row group 0..7
    int c = lane & 7;                     // feature chunk 0..7
    int off = slice * 32 + c * 4;         // fp16 element offset in row

    int s = __builtin_amdgcn_readfirstlane(rowptr[i]);
    int e = __builtin_amdgcn_readfirstlane(rowptr[i + 1]);

    float a0 = 0.f, a1 = 0.f, a2 = 0.f, a3 = 0.f;
    int k = s;
    for (; k + 16 <= e; k += 16) {        // 16 edges per iter, 2 gathers per lane
        int j0 = col[k + g];
        int j1 = col[k + 8 + g];
        f16x4 v0 = *reinterpret_cast<const f16x4*>(&T[(size_t)j0 * FDIM + off]);
        f16x4 v1 = *reinterpret_cast<const f16x4*>(&T[(size_t)j1 * FDIM + off]);
        a0 += (float)v0[0] + (float)v1[0];
        a1 += (float)v0[1] + (float)v1[1];
        a2 += (float)v0[2] + (float)v1[2];
        a3 += (float)v0[3] + (float)v1[3];
    }
    for (; k < e; k += 8) {               // masked tail
        int kk = k + g;
        if (kk < e) {
            int j = col[kk];
            f16x4 v = *reinterpret_cast<const f16x4*>(&T[(size_t)j * FDIM + off]);
            a0 += (float)v[0]; a1 += (float)v[1]; a2 += (float)v[2]; a3 += (float)v[3];
        }
    }

    // fold the 8 row groups (lane bits 3..5)
#pragma unroll
    for (int m = 8; m < 64; m <<= 1) {
        a0 += __shfl_xor(a0, m);
        a1 += __shfl_xor(a1, m);
        a2 += __shfl_xor(a2, m);
        a3 += __shfl_xor(a3, m);
    }

    if (g == 0) {                         // 8 lanes finalize 64B of output
        f16x4 sv = *reinterpret_cast<const f16x4*>(&T[(size_t)i * FDIM + off]);
        float d = dinv[i];
        float4 b = *reinterpret_cast<const float4*>(&bias[off]);
        float o0 = (a0 + (float)sv[0]) * d + b.x;
        float o1 = (a1 + (float)sv[1]) * d + b.y;
        float o2 = (a2 + (float)sv[2]) * d + b.z;
        float o3 = (a3 + (float)sv[3]) * d + b.w;
        if (RELU) {
            o0 = fmaxf(o0, 0.f); o1 = fmaxf(o1, 0.f);
            o2 = fmaxf(o2, 0.f); o3 = fmaxf(o3, 0.f);
        }
        f16x4 o = {(_Float16)o0, (_Float16)o1, (_Float16)o2, (_Float16)o3};
        *reinterpret_cast<f16x4*>(&O[(size_t)i * FDIM + off]) = o;
    }
}

// ---------------- Pool: out[g,:] += sum_{batch[i]==g} H[i,:] (batch sorted) ----------------
// wave-per-16-node chunk, lane holds 4 features; register accumulate, flush on group change.

#define PCHUNK 16

__global__ __launch_bounds__(256) void pool2_k(const _Float16* __restrict__ H,
                                               const int* __restrict__ batch,
                                               float* __restrict__ out, int Nn) {
    int wave = threadIdx.x >> 6;
    int lane = threadIdx.x & 63;
    int start = (blockIdx.x * 4 + wave) * PCHUNK;
    if (start >= Nn) return;
    int end = min(start + PCHUNK, Nn);
    int f = lane << 2;
    int cur = batch[start];
    float a0 = 0.f, a1 = 0.f, a2 = 0.f, a3 = 0.f;
    for (int n = start; n < end; ++n) {
        int g = batch[n];                    // wave-uniform
        if (g != cur) {
            atomicAdd(&out[(size_t)cur * FDIM + f + 0], a0);
            atomicAdd(&out[(size_t)cur * FDIM + f + 1], a1);
            atomicAdd(&out[(size_t)cur * FDIM + f + 2], a2);
            atomicAdd(&out[(size_t)cur * FDIM + f + 3], a3);
            a0 = a1 = a2 = a3 = 0.f;
            cur = g;
        }
        f16x4 v = *reinterpret_cast<const f16x4*>(&H[(size_t)n * FDIM + f]);
        a0 += (float)v[0]; a1 += (float)v[1]; a2 += (float)v[2]; a3 += (float)v[3];
    }
    atomicAdd(&out[(size_t)cur * FDIM + f + 0], a0);
    atomicAdd(&out[(size_t)cur * FDIM + f + 1], a1);
    atomicAdd(&out[(size_t)cur * FDIM + f + 2], a2);
    atomicAdd(&out[(size_t)cur * FDIM + f + 3], a3);
}

// ---------------- launch ----------------

extern "C" void kernel_launch(void* const* d_in, const int* in_sizes, int n_in,
                              void* d_out, int out_size, void* d_ws, size_t ws_size,
                              hipStream_t stream) {
    const float* x    = (const float*)d_in[0];
    const int*   esrc = (const int*)d_in[1];
    const int*   edst = (const int*)d_in[2];
    const int*   batch = (const int*)d_in[3];
    const float* W0 = (const float*)d_in[4];
    const float* b0 = (const float*)d_in[5];
    const float* W1 = (const float*)d_in[6];
    const float* b1 = (const float*)d_in[7];
    const float* W2 = (const float*)d_in[8];
    const float* b2 = (const float*)d_in[9];
    const float* Wo = (const float*)d_in[10];
    const float* bo = (const float*)d_in[11];
    float* out = (float*)d_out;

    const int N = in_sizes[3];
    const int E = in_sizes[1];

    // workspace layout (16B-aligned chunks)
    _Float16* h0  = (_Float16*)d_ws;
    _Float16* h1  = h0 + (size_t)N * FDIM;
    _Float16* t16 = h1 + (size_t)N * FDIM;
    _Float16* Wt  = t16 + (size_t)N * FDIM;
    float* dinv   = (float*)(Wt + 4 * 256 * 256);
    int* rowptr   = (int*)(dinv + N);
    int* counts   = rowptr + (N + 1);
    int* col      = counts + N;
    int* bsum     = col + E;
    size_t need = (size_t)((char*)(bsum + 256) - (char*)d_ws);
    if (ws_size < need) return;

    const int nbN = (N + 255) / 256;
    const int nbE = (E + 255) / 256;
    const int nscan = (N + 1023) / 1024;

    hipMemsetAsync(d_out, 0, (size_t)out_size * sizeof(float), stream);

    cast_x_k<<<(N * FDIM + 1023) / 1024, 256, 0, stream>>>(x, h0, N * FDIM);
    castW_k<<<dim3(256, 4), 256, 0, stream>>>(W0, W1, W2, Wo, Wt);

    zero_counts_k<<<nbN, 256, 0, stream>>>(counts, N);
    count_edges_k<<<nbE, 256, 0, stream>>>(esrc, counts, E);
    dinv_k<<<nbN, 256, 0, stream>>>(counts, dinv, N);
    scanA_k<<<nscan, 256, 0, stream>>>(counts, rowptr, bsum, N);
    scanB_k<<<1, 256, 0, stream>>>(bsum, nscan);
    scanC_k<<<nbN, 256, 0, stream>>>(rowptr, bsum, counts, N, E);
    fill_csr_k<<<nbE, 256, 0, stream>>>(esrc, edst, rowptr, counts, col, E);

    dim3 ggrid((N + GBM - 1) / GBM, 2);
    const int nbA = 8 * ((N + 3) / 4);     // 8 slices x node chunks

    // layer 0: h0 -> t16 -> h1 (relu)
    gemm_mfma_k<<<ggrid, 256, 0, stream>>>(h0, Wt + 0 * 65536, dinv, t16, N);
    aggs_k<1><<<nbA, 256, 0, stream>>>(t16, dinv, rowptr, col, b0, h1, N);
    // layer 1: h1 -> t16 -> h0 (relu)
    gemm_mfma_k<<<ggrid, 256, 0, stream>>>(h1, Wt + 1 * 65536, dinv, t16, N);
    aggs_k<1><<<nbA, 256, 0, stream>>>(t16, dinv, rowptr, col, b1, h0, N);
    // layer 2: h0 -> t16 -> h1 (relu)
    gemm_mfma_k<<<ggrid, 256, 0, stream>>>(h0, Wt + 2 * 65536, dinv, t16, N);
    aggs_k<1><<<nbA, 256, 0, stream>>>(t16, dinv, rowptr, col, b2, h1, N);
    // layer 3 (output): h1 -> t16 -> h0 (no relu)
    gemm_mfma_k<<<ggrid, 256, 0, stream>>>(h1, Wt + 3 * 65536, dinv, t16, N);
    aggs_k<0><<<nbA, 256, 0, stream>>>(t16, dinv, rowptr, col, bo, h0, N);

    pool2_k<<<(N + 4 * PCHUNK - 1) / (4 * PCHUNK), 256, 0, stream>>>(h0, batch, out, N);
}

// Round 15
// 516.650 us; speedup vs baseline: 1.7341x; 1.7341x over previous
//
#include <hip/hip_runtime.h>
#include <hip/hip_bf16.h>

#define FDIM 256

typedef float f32x4 __attribute__((ext_vector_type(4)));
typedef _Float16 f16x4 __attribute__((ext_vector_type(4)));
typedef _Float16 f16x8 __attribute__((ext_vector_type(8)));

// async global->LDS, 16B per lane; LDS dest is wave-uniform base + lane*16
__device__ __forceinline__ void gl_lds16(const void* g, void* l) {
    __builtin_amdgcn_global_load_lds(
        (const __attribute__((address_space(1))) unsigned int*)g,
        (__attribute__((address_space(3))) unsigned int*)l,
        16, 0, 0);
}

// ---------------- CSR build ----------------

__global__ void zero_counts_k(int* counts, int Nn) {
    int i = blockIdx.x * 256 + threadIdx.x;
    if (i < Nn) counts[i] = 0;
}

__global__ void count_edges_k(const int* __restrict__ esrc, int* counts, int Ee) {
    int e = blockIdx.x * 256 + threadIdx.x;
    if (e < Ee) atomicAdd(&counts[esrc[e]], 1);
}

__global__ void dinv_k(const int* __restrict__ counts, float* __restrict__ dinv, int Nn) {
    int i = blockIdx.x * 256 + threadIdx.x;
    if (i < Nn) dinv[i] = rsqrtf((float)(counts[i] + 1));   // +1 self-loop, always > 0
}

// exclusive scan, 1024 elems / block
__global__ __launch_bounds__(256) void scanA_k(const int* __restrict__ counts,
                                               int* __restrict__ rowptr,
                                               int* __restrict__ bsum, int Nn) {
    __shared__ int sh[256];
    int tid = threadIdx.x;
    int base = blockIdx.x * 1024 + tid * 4;
    int v[4];
#pragma unroll
    for (int j = 0; j < 4; ++j) v[j] = (base + j < Nn) ? counts[base + j] : 0;
    int ts = v[0] + v[1] + v[2] + v[3];
    sh[tid] = ts;
    __syncthreads();
    for (int off = 1; off < 256; off <<= 1) {
        int x = (tid >= off) ? sh[tid - off] : 0;
        __syncthreads();
        sh[tid] += x;
        __syncthreads();
    }
    int excl = sh[tid] - ts;
    if (tid == 255) bsum[blockIdx.x] = sh[255];
    int run = excl;
#pragma unroll
    for (int j = 0; j < 4; ++j) {
        if (base + j < Nn) rowptr[base + j] = run;
        run += v[j];
    }
}

__global__ __launch_bounds__(256) void scanB_k(int* bsum, int nb) {
    __shared__ int sh[256];
    int tid = threadIdx.x;
    int v = (tid < nb) ? bsum[tid] : 0;
    sh[tid] = v;
    __syncthreads();
    for (int off = 1; off < 256; off <<= 1) {
        int x = (tid >= off) ? sh[tid - off] : 0;
        __syncthreads();
        sh[tid] += x;
        __syncthreads();
    }
    if (tid < nb) bsum[tid] = sh[tid] - v;   // exclusive
}

__global__ void scanC_k(int* rowptr, const int* __restrict__ bsum, int* counts, int Nn, int Ee) {
    int i = blockIdx.x * 256 + threadIdx.x;
    if (i < Nn) {
        rowptr[i] += bsum[i >> 10];
        counts[i] = 0;   // reuse as fill cursors
    }
    if (i == 0) rowptr[Nn] = Ee;
}

__global__ void fill_csr_k(const int* __restrict__ esrc, const int* __restrict__ edst,
                           const int* __restrict__ rowptr, int* counts, int* col, int Ee) {
    int e = blockIdx.x * 256 + threadIdx.x;
    if (e < Ee) {
        int d = esrc[e];
        int pos = rowptr[d] + atomicAdd(&counts[d], 1);
        col[pos] = edst[e];
    }
}

// ---------------- casts ----------------

__global__ void cast_x_k(const float* __restrict__ x, _Float16* __restrict__ o, int n) {
    int i = (blockIdx.x * 256 + threadIdx.x) * 4;
    if (i < n) {
        float4 v = *reinterpret_cast<const float4*>(&x[i]);
        f16x4 h = {(_Float16)v.x, (_Float16)v.y, (_Float16)v.z, (_Float16)v.w};
        *reinterpret_cast<f16x4*>(&o[i]) = h;
    }
}

// Wt[z][n][k] = W_z[k][n], fp16
__global__ void castW_k(const float* __restrict__ W0, const float* __restrict__ W1,
                        const float* __restrict__ W2, const float* __restrict__ W3,
                        _Float16* __restrict__ Wt) {
    const float* Ws[4] = {W0, W1, W2, W3};
    const float* W = Ws[blockIdx.y];
    int n = blockIdx.x;
    int k = threadIdx.x;
    Wt[((size_t)blockIdx.y << 16) + n * 256 + k] = (_Float16)W[k * 256 + n];
}

// ---------------- MFMA GEMM: T[i,:] = dinv[i] * (H[i,:] @ W)  (fp16 in, fp16 out) ----------------
// 128x128 tile, BK=64, 4 waves (2x2), each wave 64x64 via 4x4 frags of 16x16x32.
// Staging via global_load_lds width-16: linear LDS dest + inverse-XOR'd global source,
// fragment reads use the XOR-swizzled byte address (rule: both-sides-or-neither).

#define GBM 128
#define GBK 64

__global__ __launch_bounds__(256) void gemm_mfma_k(const _Float16* __restrict__ A,
                                                   const _Float16* __restrict__ Wt,
                                                   const float* __restrict__ dinv,
                                                   _Float16* __restrict__ T, int M) {
    __shared__ __align__(16) char smem[32768];
    _Float16* As = (_Float16*)smem;            // [128][64] swizzled image
    _Float16* Bs = As + GBM * GBK;             // [128][64] swizzled image (Bs[n][k])

    int tid = threadIdx.x;
    int lane = tid & 63;
    int wave = tid >> 6;
    int wm = (wave >> 1) * 64;
    int wn = (wave & 1) * 64;
    int rowBase = blockIdx.x * GBM;
    int colBase = blockIdx.y * 128;

    f32x4 acc[4][4] = {};

    for (int k0 = 0; k0 < FDIM; k0 += GBK) {
        // stage: 1024 16B-chunks each for A and B; 4 per thread, async direct-to-LDS.
        // LDS chunk c holds logical chunk (row r=c>>3, colchunk q=(c&7)^(r&7)), so the
        // swizzled read byte = (r*128 + kk*2) ^ ((r&7)<<4) finds its data.
        // A rows beyond M read garbage from adjacent ws buffer (in-bounds); those
        // output rows are never written in the epilogue.
#pragma unroll
        for (int it = 0; it < 4; ++it) {
            int chunk = tid + it * 256;
            int r = chunk >> 3;                      // 0..127
            int kc = ((chunk & 7) ^ (r & 7)) * 8;    // inverse-swizzled col chunk
            gl_lds16(&A[(size_t)(rowBase + r) * FDIM + k0 + kc], (char*)As + chunk * 16);
            gl_lds16(&Wt[(size_t)(colBase + r) * FDIM + k0 + kc], (char*)Bs + chunk * 16);
        }
        __syncthreads();
#pragma unroll
        for (int ks = 0; ks < 2; ++ks) {
            int kk = ks * 32 + (lane >> 4) * 8;
            f16x8 af[4], bf[4];
#pragma unroll
            for (int mi = 0; mi < 4; ++mi) {
                int r = wm + mi * 16 + (lane & 15);
                int byte = (r * 128 + kk * 2) ^ ((r & 7) << 4);
                af[mi] = *reinterpret_cast<const f16x8*>((const char*)As + byte);
            }
#pragma unroll
            for (int ni = 0; ni < 4; ++ni) {
                int r = wn + ni * 16 + (lane & 15);
                int byte = (r * 128 + kk * 2) ^ ((r & 7) << 4);
                bf[ni] = *reinterpret_cast<const f16x8*>((const char*)Bs + byte);
            }
#pragma unroll
            for (int mi = 0; mi < 4; ++mi)
#pragma unroll
                for (int ni = 0; ni < 4; ++ni)
                    acc[mi][ni] = __builtin_amdgcn_mfma_f32_16x16x32_f16(af[mi], bf[ni], acc[mi][ni], 0, 0, 0);
        }
        __syncthreads();
    }

    // epilogue: dinv-scale, repack via LDS (swizzled), coalesced fp16 writes
    int cl = lane & 15, rq = lane >> 4;
#pragma unroll
    for (int mi = 0; mi < 4; ++mi) {
#pragma unroll
        for (int r = 0; r < 4; ++r) {
            int lrow = wm + mi * 16 + rq * 4 + r;
            int grow = rowBase + lrow;
            float d = dinv[min(grow, M - 1)];
#pragma unroll
            for (int ni = 0; ni < 4; ++ni) {
                int lcol = wn + ni * 16 + cl;
                int byte = (lrow * 256 + lcol * 2) ^ (((lrow >> 2) & 7) << 5);
                *reinterpret_cast<_Float16*>((char*)smem + byte) = (_Float16)(acc[mi][ni][r] * d);
            }
        }
    }
    __syncthreads();
#pragma unroll
    for (int it = 0; it < 8; ++it) {
        int chunk = tid + it * 256;          // 2048 chunks
        int r = chunk >> 4;                  // 0..127
        int c = (chunk & 15) * 8;            // 0..120
        int byte = (r * 256 + c * 2) ^ (((r >> 2) & 7) << 5);
        uint4 v = *reinterpret_cast<const uint4*>((const char*)smem + byte);
        int grow = rowBase + r;
        if (grow < M) *reinterpret_cast<uint4*>(&T[(size_t)grow * FDIM + colBase + c]) = v;
    }
}

// ---------------- Aggregation: O[i,:] = dinv[i]*(T[i,:] + sum_in T[col,:]) + b ----------------
// wave-per-node, lane holds 4 features (8B loads), 4-deep gather pipeline (round-8 best)

template <int RELU>
__global__ __launch_bounds__(256) void agg16_k(const _Float16* __restrict__ T,
                                               const float* __restrict__ dinv,
                                               const int* __restrict__ rowptr,
                                               const int* __restrict__ col,
                                               const float* __restrict__ bias,
                                               _Float16* __restrict__ O, int Nn) {
    int lane = threadIdx.x & 63;
    int i = blockIdx.x * 4 + (threadIdx.x >> 6);
    if (i >= Nn) return;
    int s = __builtin_amdgcn_readfirstlane(rowptr[i]);
    int e = __builtin_amdgcn_readfirstlane(rowptr[i + 1]);
    int f = lane << 2;   // 4 features per lane

    f16x4 sv = *reinterpret_cast<const f16x4*>(&T[(size_t)i * FDIM + f]);
    float a0 = (float)sv[0], a1 = (float)sv[1], a2 = (float)sv[2], a3 = (float)sv[3];

    int k = s;
    for (; k + 3 < e; k += 4) {
        int j0 = col[k], j1 = col[k + 1], j2 = col[k + 2], j3 = col[k + 3];
        f16x4 v0 = *reinterpret_cast<const f16x4*>(&T[(size_t)j0 * FDIM + f]);
        f16x4 v1 = *reinterpret_cast<const f16x4*>(&T[(size_t)j1 * FDIM + f]);
        f16x4 v2 = *reinterpret_cast<const f16x4*>(&T[(size_t)j2 * FDIM + f]);
        f16x4 v3 = *reinterpret_cast<const f16x4*>(&T[(size_t)j3 * FDIM + f]);
        a0 += ((float)v0[0] + (float)v1[0]) + ((float)v2[0] + (float)v3[0]);
        a1 += ((float)v0[1] + (float)v1[1]) + ((float)v2[1] + (float)v3[1]);
        a2 += ((float)v0[2] + (float)v1[2]) + ((float)v2[2] + (float)v3[2]);
        a3 += ((float)v0[3] + (float)v1[3]) + ((float)v2[3] + (float)v3[3]);
    }
    for (; k < e; ++k) {
        int j0 = col[k];
        f16x4 v0 = *reinterpret_cast<const f16x4*>(&T[(size_t)j0 * FDIM + f]);
        a0 += (float)v0[0]; a1 += (float)v0[1]; a2 += (float)v0[2]; a3 += (float)v0[3];
    }

    float d = dinv[i];
    float4 b = *reinterpret_cast<const float4*>(&bias[f]);
    a0 = a0 * d + b.x; a1 = a1 * d + b.y; a2 = a2 * d + b.z; a3 = a3 * d + b.w;
    if (RELU) {
        a0 = fmaxf(a0, 0.f); a1 = fmaxf(a1, 0.f);
        a2 = fmaxf(a2, 0.f); a3 = fmaxf(a3, 0.f);
    }
    f16x4 o = {(_Float16)a0, (_Float16)a1, (_Float16)a2, (_Float16)a3};
    *reinterpret_cast<f16x4*>(&O[(size_t)i * FDIM + f]) = o;
}

// ---------------- Pool: out[g,:] += sum_{batch[i]==g} H[i,:] (batch sorted) ----------------
// wave-per-16-node chunk, lane holds 4 features; register accumulate, flush on group change.

#define PCHUNK 16

__global__ __launch_bounds__(256) void pool2_k(const _Float16* __restrict__ H,
                                               const int* __restrict__ batch,
                                               float* __restrict__ out, int Nn) {
    int wave = threadIdx.x >> 6;
    int lane = threadIdx.x & 63;
    int start = (blockIdx.x * 4 + wave) * PCHUNK;
    if (start >= Nn) return;
    int end = min(start + PCHUNK, Nn);
    int f = lane << 2;
    int cur = batch[start];
    float a0 = 0.f, a1 = 0.f, a2 = 0.f, a3 = 0.f;
    for (int n = start; n < end; ++n) {
        int g = batch[n];                    // wave-uniform
        if (g != cur) {
            atomicAdd(&out[(size_t)cur * FDIM + f + 0], a0);
            atomicAdd(&out[(size_t)cur * FDIM + f + 1], a1);
            atomicAdd(&out[(size_t)cur * FDIM + f + 2], a2);
            atomicAdd(&out[(size_t)cur * FDIM + f + 3], a3);
            a0 = a1 = a2 = a3 = 0.f;
            cur = g;
        }
        f16x4 v = *reinterpret_cast<const f16x4*>(&H[(size_t)n * FDIM + f]);
        a0 += (float)v[0]; a1 += (float)v[1]; a2 += (float)v[2]; a3 += (float)v[3];
    }
    atomicAdd(&out[(size_t)cur * FDIM + f + 0], a0);
    atomicAdd(&out[(size_t)cur * FDIM + f + 1], a1);
    atomicAdd(&out[(size_t)cur * FDIM + f + 2], a2);
    atomicAdd(&out[(size_t)cur * FDIM + f + 3], a3);
}

// ---------------- launch ----------------

extern "C" void kernel_launch(void* const* d_in, const int* in_sizes, int n_in,
                              void* d_out, int out_size, void* d_ws, size_t ws_size,
                              hipStream_t stream) {
    const float* x    = (const float*)d_in[0];
    const int*   esrc = (const int*)d_in[1];
    const int*   edst = (const int*)d_in[2];
    const int*   batch = (const int*)d_in[3];
    const float* W0 = (const float*)d_in[4];
    const float* b0 = (const float*)d_in[5];
    const float* W1 = (const float*)d_in[6];
    const float* b1 = (const float*)d_in[7];
    const float* W2 = (const float*)d_in[8];
    const float* b2 = (const float*)d_in[9];
    const float* Wo = (const float*)d_in[10];
    const float* bo = (const float*)d_in[11];
    float* out = (float*)d_out;

    const int N = in_sizes[3];
    const int E = in_sizes[1];

    // workspace layout (16B-aligned chunks)
    _Float16* h0  = (_Float16*)d_ws;
    _Float16* h1  = h0 + (size_t)N * FDIM;
    _Float16* t16 = h1 + (size_t)N * FDIM;
    _Float16* Wt  = t16 + (size_t)N * FDIM;
    float* dinv   = (float*)(Wt + 4 * 256 * 256);
    int* rowptr   = (int*)(dinv + N);
    int* counts   = rowptr + (N + 1);
    int* col      = counts + N;
    int* bsum     = col + E;
    size_t need = (size_t)((char*)(bsum + 256) - (char*)d_ws);
    if (ws_size < need) return;

    const int nbN = (N + 255) / 256;
    const int nbE = (E + 255) / 256;
    const int nscan = (N + 1023) / 1024;

    hipMemsetAsync(d_out, 0, (size_t)out_size * sizeof(float), stream);

    cast_x_k<<<(N * FDIM + 1023) / 1024, 256, 0, stream>>>(x, h0, N * FDIM);
    castW_k<<<dim3(256, 4), 256, 0, stream>>>(W0, W1, W2, Wo, Wt);

    zero_counts_k<<<nbN, 256, 0, stream>>>(counts, N);
    count_edges_k<<<nbE, 256, 0, stream>>>(esrc, counts, E);
    dinv_k<<<nbN, 256, 0, stream>>>(counts, dinv, N);
    scanA_k<<<nscan, 256, 0, stream>>>(counts, rowptr, bsum, N);
    scanB_k<<<1, 256, 0, stream>>>(bsum, nscan);
    scanC_k<<<nbN, 256, 0, stream>>>(rowptr, bsum, counts, N, E);
    fill_csr_k<<<nbE, 256, 0, stream>>>(esrc, edst, rowptr, counts, col, E);

    dim3 ggrid((N + GBM - 1) / GBM, 2);
    const int nbA = (N + 3) / 4;

    // layer 0: h0 -> t16 -> h1 (relu)
    gemm_mfma_k<<<ggrid, 256, 0, stream>>>(h0, Wt + 0 * 65536, dinv, t16, N);
    agg16_k<1><<<nbA, 256, 0, stream>>>(t16, dinv, rowptr, col, b0, h1, N);
    // layer 1: h1 -> t16 -> h0 (relu)
    gemm_mfma_k<<<ggrid, 256, 0, stream>>>(h1, Wt + 1 * 65536, dinv, t16, N);
    agg16_k<1><<<nbA, 256, 0, stream>>>(t16, dinv, rowptr, col, b1, h0, N);
    // layer 2: h0 -> t16 -> h1 (relu)
    gemm_mfma_k<<<ggrid, 256, 0, stream>>>(h0, Wt + 2 * 65536, dinv, t16, N);
    agg16_k<1><<<nbA, 256, 0, stream>>>(t16, dinv, rowptr, col, b2, h1, N);
    // layer 3 (output): h1 -> t16 -> h0 (no relu)
    gemm_mfma_k<<<ggrid, 256, 0, stream>>>(h1, Wt + 3 * 65536, dinv, t16, N);
    agg16_k<0><<<nbA, 256, 0, stream>>>(t16, dinv, rowptr, col, bo, h0, N);

    pool2_k<<<(N + 4 * PCHUNK - 1) / (4 * PCHUNK), 256, 0, stream>>>(h0, batch, out, N);
}